// Round 8
// baseline (223.387 us; speedup 1.0000x reference)
//
#include <hip/hip_runtime.h>

// MinEuclideanDistBlock: x(32,8,4096) f32, shapelets(8,128,64) f32 -> out(32,1,128) f32
// out[b,k] = min_w sum_c sqrt( xnorm[b,c,w] + snorm[c,k] - 2*sum_s x[b,c,w+s]*h[c,k,s] )
//
// R9 -> R10 (post-mortem: the 16-wave workgroup DID deliver occupancy 18->44% as
// predicted, but __launch_bounds__(1024,4)'s min-occupancy squeeze drove VGPR to 64
// and spilled dist[] to scratch: WRITE_SIZE 2MB->345MB, dur 166us. Same failure mode
// as R4's (256,3). Structural demand ~96 fits the 16-wave hard cap of 128):
//  - ONLY change: __launch_bounds__(1024) single-arg. Flat-workgroup-size alone
//    enforces VGPR<=128 (launchability); no extra waves/EU squeeze -> no spill.
//  - Everything else identical to R9: one 1024-thread workgroup per CU (grid 8x32=256
//    = 1 block/CU), WT=512, pass-granular Bs ping-pong DMA, async x-stage split,
//    numerics unchanged (same accumulation order as R3/R5/R8).
//  - Spill tripwire: WRITE_SIZE >> 2MB or VGPR <= 64 => this branch is dead, reduce
//    per-wave dist footprint instead.

typedef short short8 __attribute__((ext_vector_type(8)));
typedef float f32x4 __attribute__((ext_vector_type(4)));

constexpr int Bn = 32, Cn = 8, Ln = 4096, Kn = 128, Sn = 64;
constexpr int Wn = Ln - Sn + 1;          // 4033
constexpr int WT = 512;                  // windows per block
constexpr int NWT = (Wn + WT - 1) / WT;  // 8
constexpr int BDIM = 1024;               // 16 waves
constexpr int XRS = 584;                 // Xr row stride (elems); 1168B = 73*16B
constexpr int PPR = 288;                 // pairs per Xr row (576 elems)
constexpr int PAIRS = 8 * PPR;           // 2304 staged pairs per channel

typedef const __attribute__((address_space(1))) unsigned int gas_u32;
typedef __attribute__((address_space(3))) unsigned int las_u32;

__device__ __forceinline__ unsigned int f2bf(float f) {
  unsigned int u = __float_as_uint(f);
  u += 0x7FFFu + ((u >> 16) & 1u);       // round-to-nearest-even
  return u >> 16;
}

// ws layout: [0, 128KB): ushort hbf[C][K][S] = bf16(-2*h), byte-swizzled ^((k&7)<<4)
//            [128KB, +4KB): float snorm[C][K]
__global__ void prep_kernel(const float* __restrict__ sh,
                            unsigned int* __restrict__ out,
                            unsigned short* __restrict__ hbf,
                            float* __restrict__ snorm) {
  int gid = blockIdx.x * blockDim.x + threadIdx.x;  // 0..4095
  out[gid] = 0x7F7FFFFFu;                           // FLT_MAX bits (Bn*Kn == 4096)
  if (gid < Cn * Kn) {
    const float4* row = (const float4*)(sh + (size_t)gid * Sn);
    char* rowb = (char*)hbf + (size_t)gid * (Sn * 2);   // 128B row
    const unsigned int sw = (gid & 7u) << 4;            // (k&7)<<4 byte swizzle
    float a = 0.f;
    #pragma unroll
    for (int i = 0; i < 16; ++i) {
      float4 v = row[i];
      a += v.x * v.x + v.y * v.y + v.z * v.z + v.w * v.w;
      unsigned int p0 = f2bf(-2.f * v.x) | (f2bf(-2.f * v.y) << 16);
      unsigned int p1 = f2bf(-2.f * v.z) | (f2bf(-2.f * v.w) << 16);
      *(uint2*)(rowb + ((8u * i) ^ sw)) = make_uint2(p0, p1);  // stays 8B-aligned
    }
    snorm[gid] = a;
  }
}

__launch_bounds__(BDIM)
__global__ void med_kernel(const float* __restrict__ x,
                           const unsigned short* __restrict__ hbf,
                           const float* __restrict__ snorm,
                           unsigned int* __restrict__ out) {
  __shared__ __align__(16) unsigned short Xr[2][8 * XRS];   // 2 x 9.1KB
  __shared__ __align__(16) unsigned short Bs[2][64 * Sn];   // 2 x 8KB (K-half each)
  __shared__ __align__(16) float xnormC[Cn * WT];           // 16KB
  __shared__ __align__(16) float snormC[Cn * Kn];           // 4KB

  const int tid  = threadIdx.x;
  const int b    = blockIdx.y;
  const int w0   = blockIdx.x * WT;
  const int lane = tid & 63;
  const int wv   = tid >> 6;     // wave 0..15
  const int quad = lane >> 4;    // 0..3
  const int n16  = lane & 15;
  const int wbase = wv * 32;     // this wave's window offset in tile (0..480)

  const float* xb = x + (size_t)b * Cn * Ln;

  // ---- B staging: linear global->LDS DMA of one pre-swizzled 8KB K-half ----
  // 512 x 16B chunks; waves 0..7 issue one chunk each lane (wave-uniform branch).
  auto stage_half = [&](int bufi, int c, int p) {
    if (tid < 512) {
      const char* src = (const char*)hbf + ((size_t)c * Kn + p * 64) * (Sn * 2);
      char* dst = (char*)&Bs[bufi][0];
      int q16 = tid * 16;
      __builtin_amdgcn_global_load_lds((gas_u32*)(src + q16), (las_u32*)(dst + q16),
                                       16, 0, 0);
    }
  };

  // ---- X staging: c-invariant index math hoisted; load early / write late ----
  int x_lds[3], x_g[3];
  #pragma unroll
  for (int rep = 0; rep < 3; ++rep) {
    int pid = tid + rep * BDIM;       // 0..3071; valid < 2304
    if (pid < PAIRS) {
      int r = pid / PPR;
      int p = pid - r * PPR;          // pair index 0..287 -> elems 2p,2p+1
      x_lds[rep] = r * XRS + 2 * p;
      x_g[rep] = w0 + r + 2 * p;
    } else {
      x_lds[rep] = -1;
      x_g[rep] = 0;
    }
  }
  float xf[3][2] = {};
  auto load_x = [&](int c) {
    const float* xc = xb + (size_t)c * Ln;
    #pragma unroll
    for (int rep = 0; rep < 3; ++rep)
      if (x_lds[rep] >= 0) {
        int i0 = x_g[rep];
        xf[rep][0] = (i0 < Ln) ? xc[i0] : 0.f;
        xf[rep][1] = (i0 + 1 < Ln) ? xc[i0 + 1] : 0.f;
      }
  };
  auto write_x = [&](int bufi) {
    #pragma unroll
    for (int rep = 0; rep < 3; ++rep)
      if (x_lds[rep] >= 0)
        *(unsigned int*)(&Xr[bufi][x_lds[rep]]) =
            f2bf(xf[rep][0]) | (f2bf(xf[rep][1]) << 16);
  };

  // snorm: 256 float4 from prep output
  if (tid < 256) ((float4*)snormC)[tid] = ((const float4*)snorm)[tid];

  // ---- prologue: stage (c=0, pass=0) into Bs[0] (DMA overlaps xnorm compute) ----
  stage_half(0, 0, 0);
  load_x(0);

  // xnorm: 1024 threads = 8c x 128 groups, 4 windows each (rolling), fp32-exact
  {
    int c  = tid >> 7;
    int m0 = (tid & 127) * 4;
    const float* xc = xb + c * Ln;
    auto xq = [&](int i) -> float {
      float v = (i < Ln) ? xc[i] : 0.f;
      return v * v;
    };
    float s0 = 0.f;
    for (int s = 0; s < Sn; ++s) s0 += xq(w0 + m0 + s);
    float s1 = s0 - xq(w0 + m0 + 0) + xq(w0 + m0 + 64);
    float s2 = s1 - xq(w0 + m0 + 1) + xq(w0 + m0 + 65);
    float s3 = s2 - xq(w0 + m0 + 2) + xq(w0 + m0 + 66);
    xnormC[c * WT + m0 + 0] = s0;
    xnormC[c * WT + m0 + 1] = s1;
    xnormC[c * WT + m0 + 2] = s2;
    xnormC[c * WT + m0 + 3] = s3;
  }
  write_x(0);
  __syncthreads();  // drains prologue DMA (implicit vmcnt(0)) + covers norm writes

  float dist[2][8][4] = {};  // [mtile][ntile2][reg] summed distance over c

  for (int c = 0; c < Cn; ++c) {
    const int xbuf = c & 1;

    // ================= phase 0: compute K-half 0, DMA K-half 1 =================
    stage_half(1, c, 1);            // async DMA pass-1 half into Bs[1]
    if (c + 1 < Cn) load_x(c + 1);  // global loads into regs, waited at write_x

    // xnorm for this wave's 32 windows (C/D row = quad*4+reg) — one b128 each
    float4 xn[2];
    #pragma unroll
    for (int mt = 0; mt < 2; ++mt)
      xn[mt] = *(const float4*)(&xnormC[c * WT + wbase + mt * 16 + quad * 4]);

    // A fragments: lane m = n16, k = quad*8+j (+ks*32); one aligned b128 each
    short8 af[2][2];
    #pragma unroll
    for (int mt = 0; mt < 2; ++mt)
      #pragma unroll
      for (int ks = 0; ks < 2; ++ks) {
        int i = wbase + mt * 16 + n16 + ks * 32 + quad * 8;
        af[mt][ks] = *(const short8*)(&Xr[xbuf][(i & 7) * XRS + (i >> 3) * 8]);
      }

    #pragma unroll
    for (int pass = 0; pass < 2; ++pass) {
      // nt-outer / mt-inner: only one (b0,b1) pair (8 VGPRs) live at a time
      const char* bsb = (const char*)&Bs[pass][0];
      #pragma unroll
      for (int nt = 0; nt < 4; ++nt) {
        int ksh = nt * 16 + n16;                    // k-row within this half: 0..63
        float sn = snormC[c * Kn + pass * 64 + ksh];
        int boff = (ksh * 128 + quad * 16) ^ ((ksh & 7) << 4);
        short8 b0 = *(const short8*)(bsb + (boff ^ 0));
        short8 b1 = *(const short8*)(bsb + (boff ^ 64));  // ks=1: +64B, swizzle-safe
        #pragma unroll
        for (int mt = 0; mt < 2; ++mt) {
          f32x4 acc;
          #pragma unroll
          for (int rg = 0; rg < 4; ++rg) acc[rg] = xn[mt][rg] + sn;
          acc = __builtin_amdgcn_mfma_f32_16x16x32_bf16(af[mt][0], b0, acc, 0, 0, 0);
          acc = __builtin_amdgcn_mfma_f32_16x16x32_bf16(af[mt][1], b1, acc, 0, 0, 0);
          // acc == d2 (norms preloaded in C, -2 folded into B)
          #pragma unroll
          for (int rg = 0; rg < 4; ++rg)
            dist[mt][pass * 4 + nt][rg] += __builtin_amdgcn_sqrtf(acc[rg]);
        }
      }

      if (pass == 0) {
        // barrier 1: publishes Bs[1] (DMA issued a full phase ago); Bs[0] now dead
        __syncthreads();
        // ============ phase 1: compute K-half 1, DMA next c's K-half 0 ============
        if (c + 1 < Cn) stage_half(0, c + 1, 0);
      }
    }

    // late half of async-STAGE: convert + write next x tile into other buffer
    if (c + 1 < Cn) write_x(xbuf ^ 1);
    __syncthreads();  // barrier 2: publishes Xr writes + drains next-c DMA
  }

  // ---- min over windows, then global combine ----
  const int wql = w0 + wbase + quad * 4;
  #pragma unroll
  for (int nt2 = 0; nt2 < 8; ++nt2) {
    float v = 3.4e38f;
    #pragma unroll
    for (int mt = 0; mt < 2; ++mt)
      #pragma unroll
      for (int rg = 0; rg < 4; ++rg) {
        int wg = wql + mt * 16 + rg;
        float d = (wg < Wn) ? dist[mt][nt2][rg] : 3.4e38f;
        v = fminf(v, d);
      }
    v = fminf(v, __shfl_xor(v, 16, 64));
    v = fminf(v, __shfl_xor(v, 32, 64));
    if (lane < 16)
      atomicMin(&out[b * Kn + nt2 * 16 + n16], __float_as_uint(v));
  }
}

extern "C" void kernel_launch(void* const* d_in, const int* in_sizes, int n_in,
                              void* d_out, int out_size, void* d_ws, size_t ws_size,
                              hipStream_t stream) {
  const float* x  = (const float*)d_in[0];
  const float* sh = (const float*)d_in[1];
  unsigned int* out = (unsigned int*)d_out;
  unsigned short* hbf = (unsigned short*)d_ws;                      // 128 KB
  float* snorm = (float*)((char*)d_ws + (size_t)Cn * Kn * Sn * 2);  // +4 KB
  hipLaunchKernelGGL(prep_kernel, dim3(16), dim3(256), 0, stream, sh, out, hbf, snorm);
  hipLaunchKernelGGL(med_kernel, dim3(NWT, Bn), dim3(BDIM), 0, stream, x, hbf, snorm, out);
}

// Round 9
// 219.966 us; speedup vs baseline: 1.0156x; 1.0156x over previous
//
#include <hip/hip_runtime.h>

// MinEuclideanDistBlock: x(32,8,4096) f32, shapelets(8,128,64) f32 -> out(32,1,128) f32
// out[b,k] = min_w sum_c sqrt( xnorm[b,c,w] + snorm[c,k] - 2*sum_s x[b,c,w+s]*h[c,k,s] )
//
// R10 -> R11 (post-mortem: VGPR=64 + 345MB spill ALSO with single-arg launch_bounds.
// Root cause identified: the backend derives target occupancy from LDS usage
// (getOccupancyWithLocalMemSize): 55.8KB LDS -> 2 groups/CU fit -> 8 waves/EU ->
// VGPR budget 64 -> dist[] spills. Padding LDS past 80KB is impossible (64KB/WG cap),
// so override the heuristic directly):
//  - ONLY change: __attribute__((amdgpu_waves_per_eu(4,4))) on med_kernel.
//    Pins waves/EU = 4 -> VGPR budget 128; inner-loop demand measured 96 (R8, same
//    structure) -> no spill, 1 x 16-wave block/CU resident = the proven R9 design
//    point (occupancy 44%) with the accumulator in registers this time.
//  - Everything else identical to R10/R9: grid 8x32=256 = 1 block/CU, WT=512,
//    pass-granular Bs ping-pong DMA, async x-stage split, numerics unchanged.
//  - Tripwire: VGPR still 64 => attribute not honored, abandon 1024-thread line.

typedef short short8 __attribute__((ext_vector_type(8)));
typedef float f32x4 __attribute__((ext_vector_type(4)));

constexpr int Bn = 32, Cn = 8, Ln = 4096, Kn = 128, Sn = 64;
constexpr int Wn = Ln - Sn + 1;          // 4033
constexpr int WT = 512;                  // windows per block
constexpr int NWT = (Wn + WT - 1) / WT;  // 8
constexpr int BDIM = 1024;               // 16 waves
constexpr int XRS = 584;                 // Xr row stride (elems); 1168B = 73*16B
constexpr int PPR = 288;                 // pairs per Xr row (576 elems)
constexpr int PAIRS = 8 * PPR;           // 2304 staged pairs per channel

typedef const __attribute__((address_space(1))) unsigned int gas_u32;
typedef __attribute__((address_space(3))) unsigned int las_u32;

__device__ __forceinline__ unsigned int f2bf(float f) {
  unsigned int u = __float_as_uint(f);
  u += 0x7FFFu + ((u >> 16) & 1u);       // round-to-nearest-even
  return u >> 16;
}

// ws layout: [0, 128KB): ushort hbf[C][K][S] = bf16(-2*h), byte-swizzled ^((k&7)<<4)
//            [128KB, +4KB): float snorm[C][K]
__global__ void prep_kernel(const float* __restrict__ sh,
                            unsigned int* __restrict__ out,
                            unsigned short* __restrict__ hbf,
                            float* __restrict__ snorm) {
  int gid = blockIdx.x * blockDim.x + threadIdx.x;  // 0..4095
  out[gid] = 0x7F7FFFFFu;                           // FLT_MAX bits (Bn*Kn == 4096)
  if (gid < Cn * Kn) {
    const float4* row = (const float4*)(sh + (size_t)gid * Sn);
    char* rowb = (char*)hbf + (size_t)gid * (Sn * 2);   // 128B row
    const unsigned int sw = (gid & 7u) << 4;            // (k&7)<<4 byte swizzle
    float a = 0.f;
    #pragma unroll
    for (int i = 0; i < 16; ++i) {
      float4 v = row[i];
      a += v.x * v.x + v.y * v.y + v.z * v.z + v.w * v.w;
      unsigned int p0 = f2bf(-2.f * v.x) | (f2bf(-2.f * v.y) << 16);
      unsigned int p1 = f2bf(-2.f * v.z) | (f2bf(-2.f * v.w) << 16);
      *(uint2*)(rowb + ((8u * i) ^ sw)) = make_uint2(p0, p1);  // stays 8B-aligned
    }
    snorm[gid] = a;
  }
}

__launch_bounds__(BDIM)
__attribute__((amdgpu_waves_per_eu(4, 4)))
__global__ void med_kernel(const float* __restrict__ x,
                           const unsigned short* __restrict__ hbf,
                           const float* __restrict__ snorm,
                           unsigned int* __restrict__ out) {
  __shared__ __align__(16) unsigned short Xr[2][8 * XRS];   // 2 x 9.1KB
  __shared__ __align__(16) unsigned short Bs[2][64 * Sn];   // 2 x 8KB (K-half each)
  __shared__ __align__(16) float xnormC[Cn * WT];           // 16KB
  __shared__ __align__(16) float snormC[Cn * Kn];           // 4KB

  const int tid  = threadIdx.x;
  const int b    = blockIdx.y;
  const int w0   = blockIdx.x * WT;
  const int lane = tid & 63;
  const int wv   = tid >> 6;     // wave 0..15
  const int quad = lane >> 4;    // 0..3
  const int n16  = lane & 15;
  const int wbase = wv * 32;     // this wave's window offset in tile (0..480)

  const float* xb = x + (size_t)b * Cn * Ln;

  // ---- B staging: linear global->LDS DMA of one pre-swizzled 8KB K-half ----
  // 512 x 16B chunks; waves 0..7 issue one chunk each lane (wave-uniform branch).
  auto stage_half = [&](int bufi, int c, int p) {
    if (tid < 512) {
      const char* src = (const char*)hbf + ((size_t)c * Kn + p * 64) * (Sn * 2);
      char* dst = (char*)&Bs[bufi][0];
      int q16 = tid * 16;
      __builtin_amdgcn_global_load_lds((gas_u32*)(src + q16), (las_u32*)(dst + q16),
                                       16, 0, 0);
    }
  };

  // ---- X staging: c-invariant index math hoisted; load early / write late ----
  int x_lds[3], x_g[3];
  #pragma unroll
  for (int rep = 0; rep < 3; ++rep) {
    int pid = tid + rep * BDIM;       // 0..3071; valid < 2304
    if (pid < PAIRS) {
      int r = pid / PPR;
      int p = pid - r * PPR;          // pair index 0..287 -> elems 2p,2p+1
      x_lds[rep] = r * XRS + 2 * p;
      x_g[rep] = w0 + r + 2 * p;
    } else {
      x_lds[rep] = -1;
      x_g[rep] = 0;
    }
  }
  float xf[3][2] = {};
  auto load_x = [&](int c) {
    const float* xc = xb + (size_t)c * Ln;
    #pragma unroll
    for (int rep = 0; rep < 3; ++rep)
      if (x_lds[rep] >= 0) {
        int i0 = x_g[rep];
        xf[rep][0] = (i0 < Ln) ? xc[i0] : 0.f;
        xf[rep][1] = (i0 + 1 < Ln) ? xc[i0 + 1] : 0.f;
      }
  };
  auto write_x = [&](int bufi) {
    #pragma unroll
    for (int rep = 0; rep < 3; ++rep)
      if (x_lds[rep] >= 0)
        *(unsigned int*)(&Xr[bufi][x_lds[rep]]) =
            f2bf(xf[rep][0]) | (f2bf(xf[rep][1]) << 16);
  };

  // snorm: 256 float4 from prep output
  if (tid < 256) ((float4*)snormC)[tid] = ((const float4*)snorm)[tid];

  // ---- prologue: stage (c=0, pass=0) into Bs[0] (DMA overlaps xnorm compute) ----
  stage_half(0, 0, 0);
  load_x(0);

  // xnorm: 1024 threads = 8c x 128 groups, 4 windows each (rolling), fp32-exact
  {
    int c  = tid >> 7;
    int m0 = (tid & 127) * 4;
    const float* xc = xb + c * Ln;
    auto xq = [&](int i) -> float {
      float v = (i < Ln) ? xc[i] : 0.f;
      return v * v;
    };
    float s0 = 0.f;
    for (int s = 0; s < Sn; ++s) s0 += xq(w0 + m0 + s);
    float s1 = s0 - xq(w0 + m0 + 0) + xq(w0 + m0 + 64);
    float s2 = s1 - xq(w0 + m0 + 1) + xq(w0 + m0 + 65);
    float s3 = s2 - xq(w0 + m0 + 2) + xq(w0 + m0 + 66);
    xnormC[c * WT + m0 + 0] = s0;
    xnormC[c * WT + m0 + 1] = s1;
    xnormC[c * WT + m0 + 2] = s2;
    xnormC[c * WT + m0 + 3] = s3;
  }
  write_x(0);
  __syncthreads();  // drains prologue DMA (implicit vmcnt(0)) + covers norm writes

  float dist[2][8][4] = {};  // [mtile][ntile2][reg] summed distance over c

  for (int c = 0; c < Cn; ++c) {
    const int xbuf = c & 1;

    // ================= phase 0: compute K-half 0, DMA K-half 1 =================
    stage_half(1, c, 1);            // async DMA pass-1 half into Bs[1]
    if (c + 1 < Cn) load_x(c + 1);  // global loads into regs, waited at write_x

    // xnorm for this wave's 32 windows (C/D row = quad*4+reg) — one b128 each
    float4 xn[2];
    #pragma unroll
    for (int mt = 0; mt < 2; ++mt)
      xn[mt] = *(const float4*)(&xnormC[c * WT + wbase + mt * 16 + quad * 4]);

    // A fragments: lane m = n16, k = quad*8+j (+ks*32); one aligned b128 each
    short8 af[2][2];
    #pragma unroll
    for (int mt = 0; mt < 2; ++mt)
      #pragma unroll
      for (int ks = 0; ks < 2; ++ks) {
        int i = wbase + mt * 16 + n16 + ks * 32 + quad * 8;
        af[mt][ks] = *(const short8*)(&Xr[xbuf][(i & 7) * XRS + (i >> 3) * 8]);
      }

    #pragma unroll
    for (int pass = 0; pass < 2; ++pass) {
      // nt-outer / mt-inner: only one (b0,b1) pair (8 VGPRs) live at a time
      const char* bsb = (const char*)&Bs[pass][0];
      #pragma unroll
      for (int nt = 0; nt < 4; ++nt) {
        int ksh = nt * 16 + n16;                    // k-row within this half: 0..63
        float sn = snormC[c * Kn + pass * 64 + ksh];
        int boff = (ksh * 128 + quad * 16) ^ ((ksh & 7) << 4);
        short8 b0 = *(const short8*)(bsb + (boff ^ 0));
        short8 b1 = *(const short8*)(bsb + (boff ^ 64));  // ks=1: +64B, swizzle-safe
        #pragma unroll
        for (int mt = 0; mt < 2; ++mt) {
          f32x4 acc;
          #pragma unroll
          for (int rg = 0; rg < 4; ++rg) acc[rg] = xn[mt][rg] + sn;
          acc = __builtin_amdgcn_mfma_f32_16x16x32_bf16(af[mt][0], b0, acc, 0, 0, 0);
          acc = __builtin_amdgcn_mfma_f32_16x16x32_bf16(af[mt][1], b1, acc, 0, 0, 0);
          // acc == d2 (norms preloaded in C, -2 folded into B)
          #pragma unroll
          for (int rg = 0; rg < 4; ++rg)
            dist[mt][pass * 4 + nt][rg] += __builtin_amdgcn_sqrtf(acc[rg]);
        }
      }

      if (pass == 0) {
        // barrier 1: publishes Bs[1] (DMA issued a full phase ago); Bs[0] now dead
        __syncthreads();
        // ============ phase 1: compute K-half 1, DMA next c's K-half 0 ============
        if (c + 1 < Cn) stage_half(0, c + 1, 0);
      }
    }

    // late half of async-STAGE: convert + write next x tile into other buffer
    if (c + 1 < Cn) write_x(xbuf ^ 1);
    __syncthreads();  // barrier 2: publishes Xr writes + drains next-c DMA
  }

  // ---- min over windows, then global combine ----
  const int wql = w0 + wbase + quad * 4;
  #pragma unroll
  for (int nt2 = 0; nt2 < 8; ++nt2) {
    float v = 3.4e38f;
    #pragma unroll
    for (int mt = 0; mt < 2; ++mt)
      #pragma unroll
      for (int rg = 0; rg < 4; ++rg) {
        int wg = wql + mt * 16 + rg;
        float d = (wg < Wn) ? dist[mt][nt2][rg] : 3.4e38f;
        v = fminf(v, d);
      }
    v = fminf(v, __shfl_xor(v, 16, 64));
    v = fminf(v, __shfl_xor(v, 32, 64));
    if (lane < 16)
      atomicMin(&out[b * Kn + nt2 * 16 + n16], __float_as_uint(v));
  }
}

extern "C" void kernel_launch(void* const* d_in, const int* in_sizes, int n_in,
                              void* d_out, int out_size, void* d_ws, size_t ws_size,
                              hipStream_t stream) {
  const float* x  = (const float*)d_in[0];
  const float* sh = (const float*)d_in[1];
  unsigned int* out = (unsigned int*)d_out;
  unsigned short* hbf = (unsigned short*)d_ws;                      // 128 KB
  float* snorm = (float*)((char*)d_ws + (size_t)Cn * Kn * Sn * 2);  // +4 KB
  hipLaunchKernelGGL(prep_kernel, dim3(16), dim3(256), 0, stream, sh, out, hbf, snorm);
  hipLaunchKernelGGL(med_kernel, dim3(NWT, Bn), dim3(BDIM), 0, stream, x, hbf, snorm, out);
}

// Round 10
// 111.573 us; speedup vs baseline: 2.0022x; 1.9715x over previous
//
#include <hip/hip_runtime.h>

// MinEuclideanDistBlock: x(32,8,4096) f32, shapelets(8,128,64) f32 -> out(32,1,128) f32
// out[b,k] = min_w sum_c sqrt( xnorm[b,c,w] + snorm[c,k] - 2*sum_s x[b,c,w+s]*h[c,k,s] )
//
// R11 -> R12 (post-mortem: waves_per_eu(4,4) NOT honored, VGPR stayed 64 -> 1024-thread
// line dead. Session VGPR data fits one model: backend VGPR budget = 512 /
// (waves/EU implied by LDS-fit WGs/CU): R3 32K->128/112, R5 47K->168/112,
// R8 31K->102/96, R9 55.8K@16w->64/64. The heuristic ignores attributes but follows
// LDS. R9 separately proved big WGs guarantee residency (occ 44%)):
//  - BDIM=512 (8 waves), WT=256, grid 16x32=512 WGs = 2/CU.
//  - LDS padded to 54.25KB: floor(160/54.25)=2 WGs -> 16 waves/CU -> 4 waves/EU
//    -> VGPR budget 128 >= measured ~112 demand of this inner loop (R5). Two 8-wave
//    WGs/CU ~= R9's residency without its 8-waves/EU register squeeze.
//  - Pad kept alive via runtime-unprovable guarded store (out==nullptr never true).
//  - Structure otherwise identical to R8: pre-swizzled hbf + global_load_lds DMA,
//    pass-granular Bs ping-pong, async x-stage split, same accumulation order.
//  - Tripwires: VGPR=64 or WRITE_SIZE>>2MB -> model wrong, revert to R5 geometry.

typedef short short8 __attribute__((ext_vector_type(8)));
typedef float f32x4 __attribute__((ext_vector_type(4)));

constexpr int Bn = 32, Cn = 8, Ln = 4096, Kn = 128, Sn = 64;
constexpr int Wn = Ln - Sn + 1;          // 4033
constexpr int WT = 256;                  // windows per block
constexpr int NWT = (Wn + WT - 1) / WT;  // 16
constexpr int BDIM = 512;                // 8 waves
constexpr int XRS = 328;                 // Xr row stride (elems); 656B = 41*16B, 164w = 4 mod 32
constexpr int PPR = 160;                 // pairs per Xr row (320 elems staged)
constexpr int PAIRS = 8 * PPR;           // 1280 staged pairs per channel

typedef const __attribute__((address_space(1))) unsigned int gas_u32;
typedef __attribute__((address_space(3))) unsigned int las_u32;

__device__ __forceinline__ unsigned int f2bf(float f) {
  unsigned int u = __float_as_uint(f);
  u += 0x7FFFu + ((u >> 16) & 1u);       // round-to-nearest-even
  return u >> 16;
}

// ws layout: [0, 128KB): ushort hbf[C][K][S] = bf16(-2*h), byte-swizzled ^((k&7)<<4)
//            [128KB, +4KB): float snorm[C][K]
__global__ void prep_kernel(const float* __restrict__ sh,
                            unsigned int* __restrict__ out,
                            unsigned short* __restrict__ hbf,
                            float* __restrict__ snorm) {
  int gid = blockIdx.x * blockDim.x + threadIdx.x;  // 0..4095
  out[gid] = 0x7F7FFFFFu;                           // FLT_MAX bits (Bn*Kn == 4096)
  if (gid < Cn * Kn) {
    const float4* row = (const float4*)(sh + (size_t)gid * Sn);
    char* rowb = (char*)hbf + (size_t)gid * (Sn * 2);   // 128B row
    const unsigned int sw = (gid & 7u) << 4;            // (k&7)<<4 byte swizzle
    float a = 0.f;
    #pragma unroll
    for (int i = 0; i < 16; ++i) {
      float4 v = row[i];
      a += v.x * v.x + v.y * v.y + v.z * v.z + v.w * v.w;
      unsigned int p0 = f2bf(-2.f * v.x) | (f2bf(-2.f * v.y) << 16);
      unsigned int p1 = f2bf(-2.f * v.z) | (f2bf(-2.f * v.w) << 16);
      *(uint2*)(rowb + ((8u * i) ^ sw)) = make_uint2(p0, p1);  // stays 8B-aligned
    }
    snorm[gid] = a;
  }
}

__launch_bounds__(BDIM)
__global__ void med_kernel(const float* __restrict__ x,
                           const unsigned short* __restrict__ hbf,
                           const float* __restrict__ snorm,
                           unsigned int* __restrict__ out) {
  __shared__ __align__(16) unsigned short Xr[2][8 * XRS];   // 2 x 5.1KB
  __shared__ __align__(16) unsigned short Bs[2][64 * Sn];   // 2 x 8KB (K-half each)
  __shared__ __align__(16) float xnormC[Cn * WT];           // 8KB
  __shared__ __align__(16) float snormC[Cn * Kn];           // 4KB
  __shared__ __align__(16) unsigned char lds_pad[16384];    // occupancy-steering pad

  const int tid  = threadIdx.x;
  const int b    = blockIdx.y;
  const int w0   = blockIdx.x * WT;
  const int lane = tid & 63;
  const int wv   = tid >> 6;     // wave 0..7
  const int quad = lane >> 4;    // 0..3
  const int n16  = lane & 15;
  const int wbase = wv * 32;     // this wave's window offset in tile (0..224)

  // keep the pad allocated: 'out' is never null at runtime, compiler can't prove it
  if (out == nullptr) lds_pad[tid & 1023] = (unsigned char)tid;

  const float* xb = x + (size_t)b * Cn * Ln;

  // ---- B staging: linear global->LDS DMA of one pre-swizzled 8KB K-half ----
  // 512 threads x one 16B chunk = 8KB.
  auto stage_half = [&](int bufi, int c, int p) {
    const char* src = (const char*)hbf + ((size_t)c * Kn + p * 64) * (Sn * 2);
    char* dst = (char*)&Bs[bufi][0];
    int q16 = tid * 16;
    __builtin_amdgcn_global_load_lds((gas_u32*)(src + q16), (las_u32*)(dst + q16),
                                     16, 0, 0);
  };

  // ---- X staging: c-invariant index math hoisted; load early / write late ----
  int x_lds[3], x_g[3];
  #pragma unroll
  for (int rep = 0; rep < 3; ++rep) {
    int pid = tid + rep * BDIM;       // 0..1535; valid < 1280
    if (pid < PAIRS) {
      int r = pid / PPR;
      int p = pid - r * PPR;          // pair index 0..159 -> elems 2p,2p+1
      x_lds[rep] = r * XRS + 2 * p;
      x_g[rep] = w0 + r + 2 * p;
    } else {
      x_lds[rep] = -1;
      x_g[rep] = 0;
    }
  }
  float xf[3][2] = {};
  auto load_x = [&](int c) {
    const float* xc = xb + (size_t)c * Ln;
    #pragma unroll
    for (int rep = 0; rep < 3; ++rep)
      if (x_lds[rep] >= 0) {
        int i0 = x_g[rep];
        xf[rep][0] = (i0 < Ln) ? xc[i0] : 0.f;
        xf[rep][1] = (i0 + 1 < Ln) ? xc[i0 + 1] : 0.f;
      }
  };
  auto write_x = [&](int bufi) {
    #pragma unroll
    for (int rep = 0; rep < 3; ++rep)
      if (x_lds[rep] >= 0)
        *(unsigned int*)(&Xr[bufi][x_lds[rep]]) =
            f2bf(xf[rep][0]) | (f2bf(xf[rep][1]) << 16);
  };

  // snorm: 256 float4 from prep output
  if (tid < 256) ((float4*)snormC)[tid] = ((const float4*)snorm)[tid];

  // ---- prologue: stage (c=0, pass=0) into Bs[0] (DMA overlaps xnorm compute) ----
  stage_half(0, 0, 0);
  load_x(0);

  // xnorm: 512 threads = 8c x 64 groups, 4 windows each (rolling), fp32-exact
  {
    int c  = tid >> 6;
    int m0 = (tid & 63) * 4;
    const float* xc = xb + c * Ln;
    auto xq = [&](int i) -> float {
      float v = (i < Ln) ? xc[i] : 0.f;
      return v * v;
    };
    float s0 = 0.f;
    for (int s = 0; s < Sn; ++s) s0 += xq(w0 + m0 + s);
    float s1 = s0 - xq(w0 + m0 + 0) + xq(w0 + m0 + 64);
    float s2 = s1 - xq(w0 + m0 + 1) + xq(w0 + m0 + 65);
    float s3 = s2 - xq(w0 + m0 + 2) + xq(w0 + m0 + 66);
    xnormC[c * WT + m0 + 0] = s0;
    xnormC[c * WT + m0 + 1] = s1;
    xnormC[c * WT + m0 + 2] = s2;
    xnormC[c * WT + m0 + 3] = s3;
  }
  write_x(0);
  __syncthreads();  // drains prologue DMA (implicit vmcnt(0)) + covers norm writes

  float dist[2][8][4] = {};  // [mtile][ntile2][reg] summed distance over c

  for (int c = 0; c < Cn; ++c) {
    const int xbuf = c & 1;

    // ================= phase 0: compute K-half 0, DMA K-half 1 =================
    stage_half(1, c, 1);            // async DMA pass-1 half into Bs[1]
    if (c + 1 < Cn) load_x(c + 1);  // global loads into regs, waited at write_x

    // xnorm for this wave's 32 windows (C/D row = quad*4+reg) — one b128 each
    float4 xn[2];
    #pragma unroll
    for (int mt = 0; mt < 2; ++mt)
      xn[mt] = *(const float4*)(&xnormC[c * WT + wbase + mt * 16 + quad * 4]);

    // A fragments: lane m = n16, k = quad*8+j (+ks*32); one aligned b128 each
    short8 af[2][2];
    #pragma unroll
    for (int mt = 0; mt < 2; ++mt)
      #pragma unroll
      for (int ks = 0; ks < 2; ++ks) {
        int i = wbase + mt * 16 + n16 + ks * 32 + quad * 8;
        af[mt][ks] = *(const short8*)(&Xr[xbuf][(i & 7) * XRS + (i >> 3) * 8]);
      }

    #pragma unroll
    for (int pass = 0; pass < 2; ++pass) {
      // nt-outer / mt-inner: only one (b0,b1) pair (8 VGPRs) live at a time
      const char* bsb = (const char*)&Bs[pass][0];
      #pragma unroll
      for (int nt = 0; nt < 4; ++nt) {
        int ksh = nt * 16 + n16;                    // k-row within this half: 0..63
        float sn = snormC[c * Kn + pass * 64 + ksh];
        int boff = (ksh * 128 + quad * 16) ^ ((ksh & 7) << 4);
        short8 b0 = *(const short8*)(bsb + (boff ^ 0));
        short8 b1 = *(const short8*)(bsb + (boff ^ 64));  // ks=1: +64B, swizzle-safe
        #pragma unroll
        for (int mt = 0; mt < 2; ++mt) {
          f32x4 acc;
          #pragma unroll
          for (int rg = 0; rg < 4; ++rg) acc[rg] = xn[mt][rg] + sn;
          acc = __builtin_amdgcn_mfma_f32_16x16x32_bf16(af[mt][0], b0, acc, 0, 0, 0);
          acc = __builtin_amdgcn_mfma_f32_16x16x32_bf16(af[mt][1], b1, acc, 0, 0, 0);
          // acc == d2 (norms preloaded in C, -2 folded into B)
          #pragma unroll
          for (int rg = 0; rg < 4; ++rg)
            dist[mt][pass * 4 + nt][rg] += __builtin_amdgcn_sqrtf(acc[rg]);
        }
      }

      if (pass == 0) {
        // barrier 1: publishes Bs[1] (DMA issued a full phase ago); Bs[0] now dead
        __syncthreads();
        // ============ phase 1: compute K-half 1, DMA next c's K-half 0 ============
        if (c + 1 < Cn) stage_half(0, c + 1, 0);
      }
    }

    // late half of async-STAGE: convert + write next x tile into other buffer
    if (c + 1 < Cn) write_x(xbuf ^ 1);
    __syncthreads();  // barrier 2: publishes Xr writes + drains next-c DMA
  }

  // ---- min over windows, then global combine ----
  const int wql = w0 + wbase + quad * 4;
  #pragma unroll
  for (int nt2 = 0; nt2 < 8; ++nt2) {
    float v = 3.4e38f;
    #pragma unroll
    for (int mt = 0; mt < 2; ++mt)
      #pragma unroll
      for (int rg = 0; rg < 4; ++rg) {
        int wg = wql + mt * 16 + rg;
        float d = (wg < Wn) ? dist[mt][nt2][rg] : 3.4e38f;
        v = fminf(v, d);
      }
    v = fminf(v, __shfl_xor(v, 16, 64));
    v = fminf(v, __shfl_xor(v, 32, 64));
    if (lane < 16)
      atomicMin(&out[b * Kn + nt2 * 16 + n16], __float_as_uint(v));
  }
}

extern "C" void kernel_launch(void* const* d_in, const int* in_sizes, int n_in,
                              void* d_out, int out_size, void* d_ws, size_t ws_size,
                              hipStream_t stream) {
  const float* x  = (const float*)d_in[0];
  const float* sh = (const float*)d_in[1];
  unsigned int* out = (unsigned int*)d_out;
  unsigned short* hbf = (unsigned short*)d_ws;                      // 128 KB
  float* snorm = (float*)((char*)d_ws + (size_t)Cn * Kn * Sn * 2);  // +4 KB
  hipLaunchKernelGGL(prep_kernel, dim3(16), dim3(256), 0, stream, sh, out, hbf, snorm);
  hipLaunchKernelGGL(med_kernel, dim3(NWT, Bn), dim3(BDIM), 0, stream, x, hbf, snorm, out);
}